// Round 1
// baseline (262.414 us; speedup 1.0000x reference)
//
#include <hip/hip_runtime.h>

// SelfAttentionHead R8: XCD-pinned attn dispatch.
//  qkv : m97-style async DMA staging, XOR-swizzled LDS, double-buffered,
//        one barrier/iter. (unchanged from R7)
//  attn: single-wave blocks, NO barriers. K/V tiles DMA'd to wave-private
//        LDS; register fragments act as the double buffer; explicit
//        s_waitcnt vmcnt/lgkmcnt via inline asm.
//        R8 change: batch = (bid&7) + 8*(slot>>7) pins 2 batches per XCD
//        (HW round-robins consecutive bids across the 8 XCDs), so each
//        XCD's L2 holds a 1.5 MB K/V/q working set instead of 8 MB (all
//        16 batches) -> K/V tile re-reads (540 MB total) become L2 hits.
//        Strip index is 7-bit bit-reversed for per-CU long/short mixing
//        under any block->CU assignment.
// Fragment maps (verified R2-R6): A[m=l15][k=Q*8+j] == B[k=Q*8+j][n=l15];
// C/D: col=l15, row=Q*4+reg. Operand swap == transposed product.
// XOR swizzle: 16B group g of row r stored at slot g^(r&15) [A, 16 groups]
// or g^(r&7) [B/K/V, 8 groups] -> frag ds_read_b128 at bank floor.

typedef __bf16 bf16x8 __attribute__((ext_vector_type(8)));
typedef __bf16 bf16x4 __attribute__((ext_vector_type(4)));
typedef float f32x4 __attribute__((ext_vector_type(4)));

constexpr int kE = 1024;
constexpr int kH = 64;
constexpr int kT = 2048;
constexpr int kB = 16;
constexpr int kM = kB * kT;
constexpr float kQScale = 0.125f * 1.44269504088896340736f;  // H^-0.5 * log2(e)

#define MFMA16(a, b, c) __builtin_amdgcn_mfma_f32_16x16x32_bf16((a), (b), (c), 0, 0, 0)

__device__ __forceinline__ void gl_lds16(const void* g, void* l) {
    __builtin_amdgcn_global_load_lds(
        (const __attribute__((address_space(1))) void*)g,
        (__attribute__((address_space(3))) void*)l, 16, 0, 0);
}

// ---------------------------------------------------------------- prep_w
__global__ __launch_bounds__(256)
void prep_w(const float* __restrict__ Wq, const float* __restrict__ Wk,
            const float* __restrict__ Wv, __bf16* __restrict__ WbT)
{
    __shared__ float tl[64][65];
    const int mat = blockIdx.x >> 4;
    const int k0 = (blockIdx.x & 15) * 64;
    const float* src = (mat == 0) ? Wq : (mat == 1) ? Wk : Wv;

    const int t = threadIdx.x;
    const int kr = t >> 2;
    const int cg = (t & 3) * 16;
    #pragma unroll
    for (int i = 0; i < 4; ++i) {
        float4 v = *(const float4*)&src[(size_t)(k0 + kr) * kH + cg + 4 * i];
        tl[cg + 4 * i + 0][kr] = v.x;
        tl[cg + 4 * i + 1][kr] = v.y;
        tl[cg + 4 * i + 2][kr] = v.z;
        tl[cg + 4 * i + 3][kr] = v.w;
    }
    __syncthreads();
    const int nl = t >> 2;
    const int kg = (t & 3) * 16;
    bf16x8 o0, o1;
    #pragma unroll
    for (int j = 0; j < 8; ++j) {
        o0[j] = (__bf16)tl[nl][kg + j];
        o1[j] = (__bf16)tl[nl][kg + 8 + j];
    }
    *(bf16x8*)&WbT[(size_t)(mat * 64 + nl) * kE + k0 + kg] = o0;
    *(bf16x8*)&WbT[(size_t)(mat * 64 + nl) * kE + k0 + kg + 8] = o1;
}

// ---------------------------------------------------------------- qkv
// 512 blocks, 256 threads (4 waves). Block: 64 rows x 192 cols (q|k|v).
// A-LDS: row r (0..63) x group g (0..15, 16B f32): byte = r*256 + (g^(r&15))*16
// B-LDS: row n (0..191) x group g (0..7, 16B bf16): byte = n*128 + (g^(n&7))*16
__global__ __launch_bounds__(256)
void qkv(const float* __restrict__ x, const __bf16* __restrict__ WbT,
         __bf16* __restrict__ qo, __bf16* __restrict__ ko, __bf16* __restrict__ vT)
{
    __shared__ __align__(16) char Ab[2][16384];
    __shared__ __align__(16) char Bb[2][24576];

    const int t = threadIdx.x;
    const int lane = t & 63;
    const int w = t >> 6;
    const int l15 = lane & 15;
    const int Q = lane >> 4;
    const int row0 = blockIdx.x * 64;

    f32x4 acc[4][3];
    #pragma unroll
    for (int mt = 0; mt < 4; ++mt)
        #pragma unroll
        for (int nt = 0; nt < 3; ++nt) acc[mt][nt] = (f32x4){0.f, 0.f, 0.f, 0.f};

    // DMA staging: per wave, A = 4 KB (4 instrs), B = 6 KB (6 instrs).
    // LDS dst = uniform base + lane*16 (HW). Data swizzled via global source.
    auto stage = [&](int p, int k0) {
        #pragma unroll
        for (int i = 0; i < 4; ++i) {
            const int row = (w * 4 + i) * 4 + (lane >> 4);          // linear row
            const int g = (lane & 15) ^ (i * 4 + (lane >> 4));      // slot^ (row&15)
            gl_lds16(&x[(size_t)(row0 + row) * kE + k0 + g * 4],
                     &Ab[p][(w * 4 + i) * 1024]);
        }
        #pragma unroll
        for (int i = 0; i < 6; ++i) {
            const int n = (w * 6 + i) * 8 + (lane >> 3);
            const int g = (lane & 7) ^ (lane >> 3);                 // slot ^ (n&7)
            gl_lds16(&WbT[(size_t)n * kE + k0 + g * 8],
                     &Bb[p][(w * 6 + i) * 1024]);
        }
    };

    stage(0, 0);
    __syncthreads();                       // vmcnt drain: chunk 0 landed

    for (int c = 0; c < 16; ++c) {
        const int p = c & 1;
        if (c < 15) stage(1 - p, (c + 1) * 64);   // async prefetch

        #pragma unroll
        for (int ks = 0; ks < 2; ++ks) {
            bf16x8 a4[4];
            #pragma unroll
            for (int mt = 0; mt < 4; ++mt) {
                const int row = mt * 16 + l15;
                float4 u0 = *(const float4*)&Ab[p][row * 256 + ((ks * 8 + Q * 2 + 0) ^ l15) * 16];
                float4 u1 = *(const float4*)&Ab[p][row * 256 + ((ks * 8 + Q * 2 + 1) ^ l15) * 16];
                bf16x8 a;
                a[0] = (__bf16)u0.x; a[1] = (__bf16)u0.y;
                a[2] = (__bf16)u0.z; a[3] = (__bf16)u0.w;
                a[4] = (__bf16)u1.x; a[5] = (__bf16)u1.y;
                a[6] = (__bf16)u1.z; a[7] = (__bf16)u1.w;
                a4[mt] = a;
            }
            #pragma unroll
            for (int nt = 0; nt < 3; ++nt) {
                const int n = w * 48 + nt * 16 + l15;
                bf16x8 b = *(const bf16x8*)&Bb[p][n * 128 + (((ks * 4 + Q) ^ (l15 & 7)) * 16)];
                #pragma unroll
                for (int mt = 0; mt < 4; ++mt)
                    acc[mt][nt] = MFMA16(a4[mt], b, acc[mt][nt]);
            }
        }
        __syncthreads();   // drains vmcnt (prefetch landed) + lgkm (buf p free)
    }

    const int batch = row0 >> 11;
    const int tr0 = row0 & 2047;
    #pragma unroll
    for (int nt = 0; nt < 3; ++nt) {
        const int col0 = w * 48 + nt * 16;
        const int mat = col0 >> 6;
        const int c = (col0 & 63) + l15;
        if (mat == 2) {
            #pragma unroll
            for (int mt = 0; mt < 4; ++mt) {
                const int trow = tr0 + mt * 16 + Q * 4;
                bf16x4 pk;
                #pragma unroll
                for (int r = 0; r < 4; ++r) pk[r] = (__bf16)acc[mt][nt][r];
                *(bf16x4*)&vT[((size_t)batch * kH + c) * kT + trow] = pk;
            }
        } else {
            __bf16* dst = (mat == 0) ? qo : ko;
            const float sc_ = (mat == 0) ? kQScale : 1.0f;
            #pragma unroll
            for (int mt = 0; mt < 4; ++mt)
                #pragma unroll
                for (int r = 0; r < 4; ++r) {
                    const size_t row = row0 + mt * 16 + Q * 4 + r;
                    dst[row * kH + c] = (__bf16)(acc[mt][nt][r] * sc_);
                }
        }
    }
}

// ---------------------------------------------------------------- attn
// 2048 single-wave blocks. R8 dispatch: HW assigns bid -> XCD (bid & 7);
// batch = (bid&7) + 8*(slot>>7) pins batches {x, x+8} to XCD x so K/V/q
// stay L2-resident (1.5 MB working set vs 4 MB L2). Strip index is 7-bit
// bit-reversed so any within-XCD block->CU grouping mixes long and short
// causal strips. Lane l15 owns q-row q16*16+l15. NO barriers: wave-private
// LDS K/V, register fragments as double buffer, explicit waitcnt.
// K-LDS: row s (0..63) x group g (0..7): byte = s*128 + (g^(s&7))*16
// V-LDS: row h (0..63) x group g (0..7): byte = h*128 + (g^(h&7))*16
__global__ __launch_bounds__(64, 2)
void attn(const __bf16* __restrict__ qm, const __bf16* __restrict__ km,
          const __bf16* __restrict__ vT, float* __restrict__ out)
{
    __shared__ __align__(16) char Kb[8192];
    __shared__ __align__(16) char Vb[8192];
    __shared__ __align__(16) __bf16 Ps[16][72];

    const int lane = threadIdx.x;
    const int l15 = lane & 15;
    const int Q = lane >> 4;

    const int xcd  = blockIdx.x & 7;          // HW XCD for this block
    const int slot = blockIdx.x >> 3;         // 0..255 within the XCD
    const int batch = xcd + ((slot >> 7) << 3);   // 2 batches pinned per XCD
    const int s = slot & 127;
    const int q16 = ((s & 1) << 6) | ((s & 2) << 4) | ((s & 4) << 2) | (s & 8)
                  | ((s & 16) >> 2) | ((s & 32) >> 4) | ((s & 64) >> 6);
    const int qrow = q16 * 16 + l15;
    const int last = q16 >> 2;

    const __bf16* qb = qm + (size_t)batch * kT * kH;
    const __bf16* kb = km + (size_t)batch * kT * kH;
    const __bf16* vb = vT + (size_t)batch * kH * kT;

    auto stage = [&](int s0) {
        #pragma unroll
        for (int i = 0; i < 8; ++i) {
            const int n = i * 8 + (lane >> 3);
            const int g = (lane & 7) ^ (lane >> 3);
            gl_lds16(&kb[(size_t)(s0 + n) * kH + g * 8], &Kb[i * 1024]);
            gl_lds16(&vb[(size_t)n * kT + s0 + g * 8], &Vb[i * 1024]);
        }
    };

    // Q fragment (B-operand of S^T)
    bf16x8 aq[2];
    aq[0] = *(const bf16x8*)&qb[(size_t)qrow * kH + Q * 8];
    aq[1] = *(const bf16x8*)&qb[(size_t)qrow * kH + 32 + Q * 8];

    f32x4 O[4];
    #pragma unroll
    for (int i = 0; i < 4; ++i) O[i] = (f32x4){0.f, 0.f, 0.f, 0.f};
    float m_ = -3.0e38f, l_ = 0.f;

    stage(0);
    asm volatile("s_waitcnt vmcnt(0)" ::: "memory");

    for (int kt = 0; kt <= last; ++kt) {
        // 1. fragments LDS -> regs (regs are the double buffer)
        bf16x8 kf[8], vf[8];
        #pragma unroll
        for (int ks = 0; ks < 2; ++ks)
            #pragma unroll
            for (int nt = 0; nt < 4; ++nt)
                kf[ks * 4 + nt] = *(const bf16x8*)
                    &Kb[(nt * 16 + l15) * 128 + (((ks * 4 + Q) ^ (l15 & 7)) * 16)];
        #pragma unroll
        for (int ht = 0; ht < 4; ++ht)
            #pragma unroll
            for (int ss = 0; ss < 2; ++ss)
                vf[ht * 2 + ss] = *(const bf16x8*)
                    &Vb[(ht * 16 + l15) * 128 + (((ss * 4 + Q) ^ (l15 & 7)) * 16)];
        asm volatile("s_waitcnt lgkmcnt(0)" ::: "memory");   // reads retired

        // 2. DMA prefetch kt+1 into the same buffers (covered by compute)
        if (kt < last) stage((kt + 1) * 64);

        // 3. S^T = K * Q^T
        f32x4 sacc[4];
        #pragma unroll
        for (int nt = 0; nt < 4; ++nt) sacc[nt] = (f32x4){0.f, 0.f, 0.f, 0.f};
        #pragma unroll
        for (int ks = 0; ks < 2; ++ks)
            #pragma unroll
            for (int nt = 0; nt < 4; ++nt)
                sacc[nt] = MFMA16(kf[ks * 4 + nt], aq[ks], sacc[nt]);

        if (kt == last) {   // diagonal tile mask
            const int s0 = kt * 64;
            #pragma unroll
            for (int nt = 0; nt < 4; ++nt)
                #pragma unroll
                for (int r = 0; r < 4; ++r)
                    if (s0 + nt * 16 + Q * 4 + r > qrow) sacc[nt][r] = -3.0e38f;
        }

        // online softmax: register reduce + 2 shuffles
        float mx = sacc[0][0];
        #pragma unroll
        for (int nt = 0; nt < 4; ++nt)
            #pragma unroll
            for (int r = 0; r < 4; ++r) mx = fmaxf(mx, sacc[nt][r]);
        mx = fmaxf(mx, __shfl_xor(mx, 16));
        mx = fmaxf(mx, __shfl_xor(mx, 32));
        const float mnew = fmaxf(m_, mx);
        const float alpha = __builtin_amdgcn_exp2f(m_ - mnew);
        float rs = 0.f;
        #pragma unroll
        for (int nt = 0; nt < 4; ++nt)
            #pragma unroll
            for (int r = 0; r < 4; ++r) {
                const float pv = __builtin_amdgcn_exp2f(sacc[nt][r] - mnew);
                sacc[nt][r] = pv;
                rs += pv;
            }
        rs += __shfl_xor(rs, 16);
        rs += __shfl_xor(rs, 32);
        l_ = l_ * alpha + rs;
        m_ = mnew;
        #pragma unroll
        for (int ht = 0; ht < 4; ++ht) O[ht] *= alpha;

        // P^T round-trip (wave-private strip; compiler orders via lgkmcnt)
        #pragma unroll
        for (int nt = 0; nt < 4; ++nt) {
            bf16x4 pk;
            #pragma unroll
            for (int r = 0; r < 4; ++r) pk[r] = (__bf16)sacc[nt][r];
            *(bf16x4*)&Ps[l15][nt * 16 + Q * 4] = pk;
        }
        bf16x8 pb0 = *(const bf16x8*)&Ps[l15][Q * 8];
        bf16x8 pb1 = *(const bf16x8*)&Ps[l15][32 + Q * 8];

        // O^T += V^T * P^T
        #pragma unroll
        for (int ht = 0; ht < 4; ++ht) {
            O[ht] = MFMA16(vf[ht * 2 + 0], pb0, O[ht]);
            O[ht] = MFMA16(vf[ht * 2 + 1], pb1, O[ht]);
        }

        // 4. prefetch landed before next iter reads LDS
        asm volatile("s_waitcnt vmcnt(0)" ::: "memory");
    }

    const float inv = 1.0f / l_;
    float* orow = out + ((size_t)batch * kT + qrow) * kH;
    #pragma unroll
    for (int ht = 0; ht < 4; ++ht) {
        float4 o4;
        o4.x = O[ht][0] * inv; o4.y = O[ht][1] * inv;
        o4.z = O[ht][2] * inv; o4.w = O[ht][3] * inv;
        *(float4*)&orow[ht * 16 + Q * 4] = o4;
    }
}

extern "C" void kernel_launch(void* const* d_in, const int* in_sizes, int n_in,
                              void* d_out, int out_size, void* d_ws, size_t ws_size,
                              hipStream_t stream)
{
    (void)in_sizes; (void)n_in; (void)out_size; (void)ws_size;
    const float* x  = (const float*)d_in[0];
    const float* Wk = (const float*)d_in[1];
    const float* Wq = (const float*)d_in[2];
    const float* Wv = (const float*)d_in[3];

    __bf16* WbT  = (__bf16*)d_ws;                     // 384 KiB
    __bf16* qb   = WbT + (size_t)192 * kE;            // 4 MiB each
    __bf16* kbuf = qb + (size_t)kM * kH;
    __bf16* vT   = kbuf + (size_t)kM * kH;

    prep_w<<<48, 256, 0, stream>>>(Wq, Wk, Wv, WbT);
    qkv<<<kM / 64, 256, 0, stream>>>(x, WbT, qb, kbuf, vT);
    attn<<<kB * 128, 64, 0, stream>>>(qb, kbuf, vT, (float*)d_out);
}

// Round 2
// 242.071 us; speedup vs baseline: 1.0840x; 1.0840x over previous
//
#include <hip/hip_runtime.h>

// SelfAttentionHead R9: shared-K/V 4-wave attn blocks.
//  qkv : m97-style async DMA staging, XOR-swizzled LDS, double-buffered,
//        one barrier/iter. (unchanged)
//  attn: R9 restructure. 512 blocks x 4 waves. The 4 causal strips
//        q16 = 4t..4t+3 all have last = t, so one block's 4 waves share
//        double-buffered K/V tiles (staged once, read 4x) with identical
//        trip counts -> K/V L2 traffic /4 (540 MB -> 135 MB), DMA issue
//        /4 (4 gl_lds16 per wave-iter). One __syncthreads per iter
//        (implicit vmcnt/lgkm drain covered by softmax+PV compute).
//        Slot interleave: even slot -> (batch=xcd,   t=slot/2),
//                         odd  slot -> (batch=xcd+8, t=31-slot/2)
//        pairs long with short blocks per CU; XCD batch pinning kept.
// Fragment maps (verified R2-R6): A[m=l15][k=Q*8+j] == B[k=Q*8+j][n=l15];
// C/D: col=l15, row=Q*4+reg. Operand swap == transposed product.
// XOR swizzle: 16B group g of row r stored at slot g^(r&15) [A, 16 groups]
// or g^(r&7) [B/K/V, 8 groups] -> frag ds_read_b128 at bank floor.

typedef __bf16 bf16x8 __attribute__((ext_vector_type(8)));
typedef __bf16 bf16x4 __attribute__((ext_vector_type(4)));
typedef float f32x4 __attribute__((ext_vector_type(4)));

constexpr int kE = 1024;
constexpr int kH = 64;
constexpr int kT = 2048;
constexpr int kB = 16;
constexpr int kM = kB * kT;
constexpr float kQScale = 0.125f * 1.44269504088896340736f;  // H^-0.5 * log2(e)

#define MFMA16(a, b, c) __builtin_amdgcn_mfma_f32_16x16x32_bf16((a), (b), (c), 0, 0, 0)

__device__ __forceinline__ void gl_lds16(const void* g, void* l) {
    __builtin_amdgcn_global_load_lds(
        (const __attribute__((address_space(1))) void*)g,
        (__attribute__((address_space(3))) void*)l, 16, 0, 0);
}

// ---------------------------------------------------------------- prep_w
__global__ __launch_bounds__(256)
void prep_w(const float* __restrict__ Wq, const float* __restrict__ Wk,
            const float* __restrict__ Wv, __bf16* __restrict__ WbT)
{
    __shared__ float tl[64][65];
    const int mat = blockIdx.x >> 4;
    const int k0 = (blockIdx.x & 15) * 64;
    const float* src = (mat == 0) ? Wq : (mat == 1) ? Wk : Wv;

    const int t = threadIdx.x;
    const int kr = t >> 2;
    const int cg = (t & 3) * 16;
    #pragma unroll
    for (int i = 0; i < 4; ++i) {
        float4 v = *(const float4*)&src[(size_t)(k0 + kr) * kH + cg + 4 * i];
        tl[cg + 4 * i + 0][kr] = v.x;
        tl[cg + 4 * i + 1][kr] = v.y;
        tl[cg + 4 * i + 2][kr] = v.z;
        tl[cg + 4 * i + 3][kr] = v.w;
    }
    __syncthreads();
    const int nl = t >> 2;
    const int kg = (t & 3) * 16;
    bf16x8 o0, o1;
    #pragma unroll
    for (int j = 0; j < 8; ++j) {
        o0[j] = (__bf16)tl[nl][kg + j];
        o1[j] = (__bf16)tl[nl][kg + 8 + j];
    }
    *(bf16x8*)&WbT[(size_t)(mat * 64 + nl) * kE + k0 + kg] = o0;
    *(bf16x8*)&WbT[(size_t)(mat * 64 + nl) * kE + k0 + kg + 8] = o1;
}

// ---------------------------------------------------------------- qkv
// 512 blocks, 256 threads (4 waves). Block: 64 rows x 192 cols (q|k|v).
// A-LDS: row r (0..63) x group g (0..15, 16B f32): byte = r*256 + (g^(r&15))*16
// B-LDS: row n (0..191) x group g (0..7, 16B bf16): byte = n*128 + (g^(n&7))*16
__global__ __launch_bounds__(256)
void qkv(const float* __restrict__ x, const __bf16* __restrict__ WbT,
         __bf16* __restrict__ qo, __bf16* __restrict__ ko, __bf16* __restrict__ vT)
{
    __shared__ __align__(16) char Ab[2][16384];
    __shared__ __align__(16) char Bb[2][24576];

    const int t = threadIdx.x;
    const int lane = t & 63;
    const int w = t >> 6;
    const int l15 = lane & 15;
    const int Q = lane >> 4;
    const int row0 = blockIdx.x * 64;

    f32x4 acc[4][3];
    #pragma unroll
    for (int mt = 0; mt < 4; ++mt)
        #pragma unroll
        for (int nt = 0; nt < 3; ++nt) acc[mt][nt] = (f32x4){0.f, 0.f, 0.f, 0.f};

    // DMA staging: per wave, A = 4 KB (4 instrs), B = 6 KB (6 instrs).
    // LDS dst = uniform base + lane*16 (HW). Data swizzled via global source.
    auto stage = [&](int p, int k0) {
        #pragma unroll
        for (int i = 0; i < 4; ++i) {
            const int row = (w * 4 + i) * 4 + (lane >> 4);          // linear row
            const int g = (lane & 15) ^ (i * 4 + (lane >> 4));      // slot^ (row&15)
            gl_lds16(&x[(size_t)(row0 + row) * kE + k0 + g * 4],
                     &Ab[p][(w * 4 + i) * 1024]);
        }
        #pragma unroll
        for (int i = 0; i < 6; ++i) {
            const int n = (w * 6 + i) * 8 + (lane >> 3);
            const int g = (lane & 7) ^ (lane >> 3);                 // slot ^ (n&7)
            gl_lds16(&WbT[(size_t)n * kE + k0 + g * 8],
                     &Bb[p][(w * 6 + i) * 1024]);
        }
    };

    stage(0, 0);
    __syncthreads();                       // vmcnt drain: chunk 0 landed

    for (int c = 0; c < 16; ++c) {
        const int p = c & 1;
        if (c < 15) stage(1 - p, (c + 1) * 64);   // async prefetch

        #pragma unroll
        for (int ks = 0; ks < 2; ++ks) {
            bf16x8 a4[4];
            #pragma unroll
            for (int mt = 0; mt < 4; ++mt) {
                const int row = mt * 16 + l15;
                float4 u0 = *(const float4*)&Ab[p][row * 256 + ((ks * 8 + Q * 2 + 0) ^ l15) * 16];
                float4 u1 = *(const float4*)&Ab[p][row * 256 + ((ks * 8 + Q * 2 + 1) ^ l15) * 16];
                bf16x8 a;
                a[0] = (__bf16)u0.x; a[1] = (__bf16)u0.y;
                a[2] = (__bf16)u0.z; a[3] = (__bf16)u0.w;
                a[4] = (__bf16)u1.x; a[5] = (__bf16)u1.y;
                a[6] = (__bf16)u1.z; a[7] = (__bf16)u1.w;
                a4[mt] = a;
            }
            #pragma unroll
            for (int nt = 0; nt < 3; ++nt) {
                const int n = w * 48 + nt * 16 + l15;
                bf16x8 b = *(const bf16x8*)&Bb[p][n * 128 + (((ks * 4 + Q) ^ (l15 & 7)) * 16)];
                #pragma unroll
                for (int mt = 0; mt < 4; ++mt)
                    acc[mt][nt] = MFMA16(a4[mt], b, acc[mt][nt]);
            }
        }
        __syncthreads();   // drains vmcnt (prefetch landed) + lgkm (buf p free)
    }

    const int batch = row0 >> 11;
    const int tr0 = row0 & 2047;
    #pragma unroll
    for (int nt = 0; nt < 3; ++nt) {
        const int col0 = w * 48 + nt * 16;
        const int mat = col0 >> 6;
        const int c = (col0 & 63) + l15;
        if (mat == 2) {
            #pragma unroll
            for (int mt = 0; mt < 4; ++mt) {
                const int trow = tr0 + mt * 16 + Q * 4;
                bf16x4 pk;
                #pragma unroll
                for (int r = 0; r < 4; ++r) pk[r] = (__bf16)acc[mt][nt][r];
                *(bf16x4*)&vT[((size_t)batch * kH + c) * kT + trow] = pk;
            }
        } else {
            __bf16* dst = (mat == 0) ? qo : ko;
            const float sc_ = (mat == 0) ? kQScale : 1.0f;
            #pragma unroll
            for (int mt = 0; mt < 4; ++mt)
                #pragma unroll
                for (int r = 0; r < 4; ++r) {
                    const size_t row = row0 + mt * 16 + Q * 4 + r;
                    dst[row * kH + c] = (__bf16)(acc[mt][nt][r] * sc_);
                }
        }
    }
}

// ---------------------------------------------------------------- attn
// R9: 512 blocks x 256 threads (4 waves). Block t handles q-rows
// [64t, 64t+64) of one batch; wave w owns strip q16 = 4t + w. All 4
// strips share last = t, so the block iterates kt = 0..t in lockstep over
// double-buffered shared K/V tiles (staged once per block-iter, 4
// gl_lds16 per wave). One __syncthreads per iter: its implicit
// vmcnt/lgkm drain is covered by softmax+PV compute.
// Dispatch: xcd = bid&7 (HW round-robin), slot = bid>>3 (0..63):
//   even slot -> batch = xcd,     t = slot/2
//   odd  slot -> batch = xcd + 8, t = 31 - slot/2   (long/short pairing)
// K-LDS: row s (0..63) x group g (0..7): byte = s*128 + (g^(s&7))*16
// V-LDS: row h (0..63) x group g (0..7): byte = h*128 + (g^(h&7))*16
__global__ __launch_bounds__(256, 2)
void attn(const __bf16* __restrict__ qm, const __bf16* __restrict__ km,
          const __bf16* __restrict__ vT, float* __restrict__ out)
{
    __shared__ __align__(16) char Kb[2][8192];
    __shared__ __align__(16) char Vb[2][8192];
    __shared__ __align__(16) __bf16 Ps[4][16][72];

    const int tid = threadIdx.x;
    const int lane = tid & 63;
    const int w = tid >> 6;
    const int l15 = lane & 15;
    const int Q = lane >> 4;

    const int xcd  = blockIdx.x & 7;
    const int slot = blockIdx.x >> 3;
    const int batch = xcd + ((slot & 1) << 3);
    const int tt = (slot & 1) ? (31 - (slot >> 1)) : (slot >> 1);
    const int q16 = tt * 4 + w;
    const int qrow = q16 * 16 + l15;
    const int last = tt;

    const __bf16* qb = qm + (size_t)batch * kT * kH;
    const __bf16* kb = km + (size_t)batch * kT * kH;
    const __bf16* vb = vT + (size_t)batch * kH * kT;

    // Staging split 4 ways: wave w covers rows [16w, 16w+16) of K and V.
    // Per instr: 8 rows (64 lanes x 16 B = 1 KB), swizzle via global src.
    auto stage = [&](int p, int s0) {
        #pragma unroll
        for (int i = 0; i < 2; ++i) {
            const int r = w * 16 + i * 8 + (lane >> 3);   // linear row
            const int g = (lane & 7) ^ (lane >> 3);       // slot ^ (r&7)
            gl_lds16(&kb[(size_t)(s0 + r) * kH + g * 8],
                     &Kb[p][(w * 2 + i) * 1024]);
            gl_lds16(&vb[(size_t)r * kT + s0 + g * 8],
                     &Vb[p][(w * 2 + i) * 1024]);
        }
    };

    // Q fragment (B-operand of S^T)
    bf16x8 aq[2];
    aq[0] = *(const bf16x8*)&qb[(size_t)qrow * kH + Q * 8];
    aq[1] = *(const bf16x8*)&qb[(size_t)qrow * kH + 32 + Q * 8];

    f32x4 O[4];
    #pragma unroll
    for (int i = 0; i < 4; ++i) O[i] = (f32x4){0.f, 0.f, 0.f, 0.f};
    float m_ = -3.0e38f, l_ = 0.f;

    stage(0, 0);
    __syncthreads();                       // tile 0 landed (vmcnt drain)

    for (int kt = 0; kt <= last; ++kt) {
        const int p = kt & 1;

        // 1. fragments LDS -> regs (all waves read the shared tile)
        bf16x8 kf[8], vf[8];
        #pragma unroll
        for (int ks = 0; ks < 2; ++ks)
            #pragma unroll
            for (int nt = 0; nt < 4; ++nt)
                kf[ks * 4 + nt] = *(const bf16x8*)
                    &Kb[p][(nt * 16 + l15) * 128 + (((ks * 4 + Q) ^ (l15 & 7)) * 16)];
        #pragma unroll
        for (int ht = 0; ht < 4; ++ht)
            #pragma unroll
            for (int ss = 0; ss < 2; ++ss)
                vf[ht * 2 + ss] = *(const bf16x8*)
                    &Vb[p][(ht * 16 + l15) * 128 + (((ss * 4 + Q) ^ (l15 & 7)) * 16)];
        asm volatile("s_waitcnt lgkmcnt(0)" ::: "memory");   // reads retired

        // 2. DMA prefetch kt+1 into the other buffer (covered by compute)
        if (kt < last) stage(1 - p, (kt + 1) * 64);

        // 3. S^T = K * Q^T
        f32x4 sacc[4];
        #pragma unroll
        for (int nt = 0; nt < 4; ++nt) sacc[nt] = (f32x4){0.f, 0.f, 0.f, 0.f};
        #pragma unroll
        for (int ks = 0; ks < 2; ++ks)
            #pragma unroll
            for (int nt = 0; nt < 4; ++nt)
                sacc[nt] = MFMA16(kf[ks * 4 + nt], aq[ks], sacc[nt]);

        if (kt == last) {   // diagonal tile mask (per-wave qrow)
            const int s0 = kt * 64;
            #pragma unroll
            for (int nt = 0; nt < 4; ++nt)
                #pragma unroll
                for (int r = 0; r < 4; ++r)
                    if (s0 + nt * 16 + Q * 4 + r > qrow) sacc[nt][r] = -3.0e38f;
        }

        // online softmax: register reduce + 2 shuffles
        float mx = sacc[0][0];
        #pragma unroll
        for (int nt = 0; nt < 4; ++nt)
            #pragma unroll
            for (int r = 0; r < 4; ++r) mx = fmaxf(mx, sacc[nt][r]);
        mx = fmaxf(mx, __shfl_xor(mx, 16));
        mx = fmaxf(mx, __shfl_xor(mx, 32));
        const float mnew = fmaxf(m_, mx);
        const float alpha = __builtin_amdgcn_exp2f(m_ - mnew);
        float rs = 0.f;
        #pragma unroll
        for (int nt = 0; nt < 4; ++nt)
            #pragma unroll
            for (int r = 0; r < 4; ++r) {
                const float pv = __builtin_amdgcn_exp2f(sacc[nt][r] - mnew);
                sacc[nt][r] = pv;
                rs += pv;
            }
        rs += __shfl_xor(rs, 16);
        rs += __shfl_xor(rs, 32);
        l_ = l_ * alpha + rs;
        m_ = mnew;
        #pragma unroll
        for (int ht = 0; ht < 4; ++ht) O[ht] *= alpha;

        // P^T round-trip (per-wave strip; compiler orders via lgkmcnt)
        #pragma unroll
        for (int nt = 0; nt < 4; ++nt) {
            bf16x4 pk;
            #pragma unroll
            for (int r = 0; r < 4; ++r) pk[r] = (__bf16)sacc[nt][r];
            *(bf16x4*)&Ps[w][l15][nt * 16 + Q * 4] = pk;
        }
        bf16x8 pb0 = *(const bf16x8*)&Ps[w][l15][Q * 8];
        bf16x8 pb1 = *(const bf16x8*)&Ps[w][l15][32 + Q * 8];

        // O^T += V^T * P^T
        #pragma unroll
        for (int ht = 0; ht < 4; ++ht) {
            O[ht] = MFMA16(vf[ht * 2 + 0], pb0, O[ht]);
            O[ht] = MFMA16(vf[ht * 2 + 1], pb1, O[ht]);
        }

        // 4. barrier: drains own vmcnt (prefetch landed for all waves) and
        //    guarantees every wave's reads of buf[p] retired before kt+2
        //    staging overwrites it.
        __syncthreads();
    }

    const float inv = 1.0f / l_;
    float* orow = out + ((size_t)batch * kT + qrow) * kH;
    #pragma unroll
    for (int ht = 0; ht < 4; ++ht) {
        float4 o4;
        o4.x = O[ht][0] * inv; o4.y = O[ht][1] * inv;
        o4.z = O[ht][2] * inv; o4.w = O[ht][3] * inv;
        *(float4*)&orow[ht * 16 + Q * 4] = o4;
    }
}

extern "C" void kernel_launch(void* const* d_in, const int* in_sizes, int n_in,
                              void* d_out, int out_size, void* d_ws, size_t ws_size,
                              hipStream_t stream)
{
    (void)in_sizes; (void)n_in; (void)out_size; (void)ws_size;
    const float* x  = (const float*)d_in[0];
    const float* Wk = (const float*)d_in[1];
    const float* Wq = (const float*)d_in[2];
    const float* Wv = (const float*)d_in[3];

    __bf16* WbT  = (__bf16*)d_ws;                     // 384 KiB
    __bf16* qb   = WbT + (size_t)192 * kE;            // 4 MiB each
    __bf16* kbuf = qb + (size_t)kM * kH;
    __bf16* vT   = kbuf + (size_t)kM * kH;

    prep_w<<<48, 256, 0, stream>>>(Wq, Wk, Wv, WbT);
    qkv<<<kM / 64, 256, 0, stream>>>(x, WbT, qb, kbuf, vT);
    attn<<<512, 256, 0, stream>>>(qb, kbuf, vT, (float*)d_out);
}